// Round 1
// baseline (177.146 us; speedup 1.0000x reference)
//
#include <hip/hip_runtime.h>

// NaiveCollider: N=8192 bodies, 2D circle collision with ordered compaction
// semantics (jnp.nonzero row-major order, truncation at 4N broad / N narrow).

constexpr int NB = 8192;
constexpr float EPS = 1e-12f;

__global__ void copy_out_kernel(const float* __restrict__ centers,
                                float* __restrict__ out) {
    int t = blockIdx.x * blockDim.x + threadIdx.x;
    if (t < NB * 2) out[t] = centers[t];
}

// One wave (64 lanes) per row i: count AABB overlaps with j > i.
__global__ void broad_count_kernel(const float2* __restrict__ centers,
                                   const float* __restrict__ radii,
                                   int* __restrict__ row_count) {
    const int wave = (blockIdx.x * blockDim.x + threadIdx.x) >> 6;
    const int lane = threadIdx.x & 63;
    if (wave >= NB) return;
    const int i = wave;
    const float2 ci = centers[i];
    const float ri = radii[i];
    int cnt = 0;
    for (int jb = i + 1; jb < NB; jb += 64) {
        const int j = jb + lane;
        bool ov = false;
        if (j < NB) {
            const float2 cj = centers[j];
            const float rs = ri + radii[j];
            ov = (fabsf(ci.x - cj.x) <= rs) && (fabsf(ci.y - cj.y) <= rs);
        }
        cnt += __popcll(__ballot(ov));
    }
    if (lane == 0) row_count[i] = cnt;
}

// Exclusive scan of 8192 ints in one block; out[8192] = total.
__global__ __launch_bounds__(1024) void scan8192_kernel(const int* __restrict__ in,
                                                        int* __restrict__ out) {
    __shared__ int bs[1024];
    const int t = threadIdx.x;
    int v[8];
    int local = 0;
#pragma unroll
    for (int k = 0; k < 8; ++k) { v[k] = in[t * 8 + k]; local += v[k]; }
    bs[t] = local;
    __syncthreads();
    for (int off = 1; off < 1024; off <<= 1) {
        int add = (t >= off) ? bs[t - off] : 0;
        __syncthreads();
        if (t >= off) bs[t] += add;
        __syncthreads();
    }
    int run = (t == 0) ? 0 : bs[t - 1];
#pragma unroll
    for (int k = 0; k < 8; ++k) { out[t * 8 + k] = run; run += v[k]; }
    if (t == 1023) out[NB] = bs[1023];
}

// One wave per row: count narrow-phase hits among broad candidates with
// global broad index < limit_broad.
__global__ void hit_count_kernel(const float2* __restrict__ centers,
                                 const float* __restrict__ radii,
                                 const int* __restrict__ row_start,
                                 const int* __restrict__ limit_broad_p,
                                 int* __restrict__ hit_count) {
    const int wave = (blockIdx.x * blockDim.x + threadIdx.x) >> 6;
    const int lane = threadIdx.x & 63;
    if (wave >= NB) return;
    const int i = wave;
    const int LB = *limit_broad_p;
    const int g0 = row_start[i];
    const float2 ci = centers[i];
    const float ri = radii[i];
    const unsigned long long lmask = (1ull << lane) - 1ull;
    int rank = 0;  // broad rank within row (wave-uniform after each chunk)
    int hits = 0;
    for (int jb = i + 1; jb < NB && g0 + rank < LB; jb += 64) {
        const int j = jb + lane;
        bool ov = false;
        float dx = 0.f, dy = 0.f, rs = 0.f;
        if (j < NB) {
            const float2 cj = centers[j];
            rs = ri + radii[j];
            dx = cj.x - ci.x;
            dy = cj.y - ci.y;
            ov = (fabsf(dx) <= rs) && (fabsf(dy) <= rs);
        }
        const unsigned long long m = __ballot(ov);
        const int myrank = rank + __popcll(m & lmask);
        bool hit = false;
        if (ov && (g0 + myrank < LB)) {
            const float dist = sqrtf(dx * dx + dy * dy + EPS);
            hit = (rs - dist) > 0.f;
        }
        hits += __popcll(__ballot(hit));
        rank += __popcll(m);
    }
    if (lane == 0) hit_count[i] = hits;
}

// One wave per row: emit hits with global hit rank < limit_narrow, scatter.
__global__ void resolve_kernel(const float2* __restrict__ centers,
                               const float* __restrict__ radii,
                               const int* __restrict__ row_start,
                               const int* __restrict__ hit_start,
                               const int* __restrict__ limit_broad_p,
                               const int* __restrict__ limit_narrow_p,
                               float* __restrict__ out) {
    const int wave = (blockIdx.x * blockDim.x + threadIdx.x) >> 6;
    const int lane = threadIdx.x & 63;
    if (wave >= NB) return;
    const int i = wave;
    const int LB = *limit_broad_p;
    const int LN = *limit_narrow_p;
    const int g0 = row_start[i];
    const int h0 = hit_start[i];
    const float2 ci = centers[i];
    const float ri = radii[i];
    const unsigned long long lmask = (1ull << lane) - 1ull;
    int rank = 0;
    int hloc = 0;
    float six = 0.f, siy = 0.f;  // accumulated delta for body i (this wave owns row i)
    for (int jb = i + 1; jb < NB; jb += 64) {
        if (g0 + rank >= LB) break;
        if (h0 + hloc >= LN) break;
        const int j = jb + lane;
        bool ov = false;
        float dx = 0.f, dy = 0.f, rs = 0.f;
        if (j < NB) {
            const float2 cj = centers[j];
            rs = ri + radii[j];
            dx = cj.x - ci.x;
            dy = cj.y - ci.y;
            ov = (fabsf(dx) <= rs) && (fabsf(dy) <= rs);
        }
        const unsigned long long m = __ballot(ov);
        const int myrank = rank + __popcll(m & lmask);
        bool hit = false;
        float dist = 1.f, depth = 0.f;
        if (ov && (g0 + myrank < LB)) {
            dist = sqrtf(dx * dx + dy * dy + EPS);
            depth = rs - dist;
            hit = depth > 0.f;
        }
        const unsigned long long hm = __ballot(hit);
        if (hit) {
            const int myh = h0 + hloc + __popcll(hm & lmask);
            if (myh < LN) {
                const float s = 0.5f * depth / dist;
                const float px = s * dx, py = s * dy;
                six -= px;
                siy -= py;
                atomicAdd(&out[2 * j],     px);
                atomicAdd(&out[2 * j + 1], py);
            }
        }
        hloc += __popcll(hm);
        rank += __popcll(m);
    }
    // wave-reduce body-i delta, single atomic from lane 0
#pragma unroll
    for (int off = 32; off > 0; off >>= 1) {
        six += __shfl_down(six, off);
        siy += __shfl_down(siy, off);
    }
    if (lane == 0 && (six != 0.f || siy != 0.f)) {
        atomicAdd(&out[2 * i],     six);
        atomicAdd(&out[2 * i + 1], siy);
    }
}

extern "C" void kernel_launch(void* const* d_in, const int* in_sizes, int n_in,
                              void* d_out, int out_size, void* d_ws, size_t ws_size,
                              hipStream_t stream) {
    const float* centers = (const float*)d_in[0];
    const float* radii   = (const float*)d_in[1];
    const int* limit_broad_p  = (const int*)d_in[2];
    const int* limit_narrow_p = (const int*)d_in[3];
    float* out = (float*)d_out;

    int* ws = (int*)d_ws;
    int* row_count = ws;                    // 8192
    int* row_start = row_count + NB;        // 8193
    int* hit_count = row_start + NB + 1;    // 8192
    int* hit_start = hit_count + NB;        // 8193

    const float2* c2 = (const float2*)centers;

    copy_out_kernel<<<(NB * 2 + 255) / 256, 256, 0, stream>>>(centers, out);
    broad_count_kernel<<<NB / 4, 256, 0, stream>>>(c2, radii, row_count);
    scan8192_kernel<<<1, 1024, 0, stream>>>(row_count, row_start);
    hit_count_kernel<<<NB / 4, 256, 0, stream>>>(c2, radii, row_start,
                                                 limit_broad_p, hit_count);
    scan8192_kernel<<<1, 1024, 0, stream>>>(hit_count, hit_start);
    resolve_kernel<<<NB / 4, 256, 0, stream>>>(c2, radii, row_start, hit_start,
                                               limit_broad_p, limit_narrow_p, out);
}